// Round 13
// baseline (190.549 us; speedup 1.0000x reference)
//
#include <hip/hip_runtime.h>

#define B_SZ   512
#define VFD    4096
#define HIDD   2048
#define EMBD   300
#define NLAB   2000
#define NPAD   320

#define G1_SPLIT 4          // gemm1 k-chunks: K=4096 -> 1024 each, 512 blocks
#define G2_SPLIT 8          // gemm2 k-chunks: K=2048 -> 256 each, 320 blocks
#define SD_SPLIT 4          // scores d-quarters: 320 -> 80 dims each

typedef __attribute__((ext_vector_type(8))) short short8x;
typedef __attribute__((ext_vector_type(4))) float f32x4;
typedef __attribute__((ext_vector_type(8))) unsigned short ushort8;

typedef const __attribute__((address_space(1))) unsigned int* gas_t;
typedef __attribute__((address_space(3))) unsigned int* las_t;

__device__ inline unsigned short f2bf(float x) {
    unsigned u = __float_as_uint(x);
    u += 0x7FFF + ((u >> 16) & 1);          // round-to-nearest-even
    return (unsigned short)(u >> 16);
}
__device__ inline unsigned pack2relu(float a, float b) {
    return (unsigned)f2bf(fmaxf(a, 0.f)) | ((unsigned)f2bf(fmaxf(b, 0.f)) << 16);
}

// ---------------------------------------------------------------------------
// Prep (5406 blocks):
//   [0,1024):     Xb = bf16(relu(vfs))
//   [1024,3072):  W1T[n][k] = bf16(W1[k][n])  (pair-packed transpose)
//   [3072,3232):  W2T[n][k] = bf16(W2[k][n]), n>=300 zero-padded
//   [3232,4232):  scores <- 0       (atomic target for scores_part)
//   [4232,4382):  E[m][n] <- b2[n]  (atomic target for gemm2)
//   [4382,5406):  H[m][k] <- b1[k]  (fp32 atomic target for gemm1)
// ---------------------------------------------------------------------------
__global__ __launch_bounds__(256) void prep_kernel(
    const float* __restrict__ vfs, unsigned short* __restrict__ Xb,
    const float* __restrict__ W1, unsigned short* __restrict__ W1T,
    const float* __restrict__ W2, unsigned short* __restrict__ W2T,
    float* __restrict__ scores, const float* __restrict__ b2,
    float* __restrict__ E, const float* __restrict__ b1,
    float* __restrict__ H)
{
    __shared__ unsigned int Lds[64][34];
    const int tid = threadIdx.x;
    const int blk = blockIdx.x;

    if (blk < 1024) {                       // Xb
        const int i = (blk * 256 + tid) * 8;
        float4 a = *(const float4*)&vfs[i];
        float4 b = *(const float4*)&vfs[i + 4];
        ushort8 o;
        o[0] = f2bf(fmaxf(a.x, 0.f)); o[1] = f2bf(fmaxf(a.y, 0.f));
        o[2] = f2bf(fmaxf(a.z, 0.f)); o[3] = f2bf(fmaxf(a.w, 0.f));
        o[4] = f2bf(fmaxf(b.x, 0.f)); o[5] = f2bf(fmaxf(b.y, 0.f));
        o[6] = f2bf(fmaxf(b.z, 0.f)); o[7] = f2bf(fmaxf(b.w, 0.f));
        *(ushort8*)&Xb[i] = o;
        return;
    }
    if (blk >= 4382) {                      // H = b1 broadcast
        const int i = ((blk - 4382) * 256 + tid) * 4;
        const int col = i & (HIDD - 1);
        *(float4*)&H[i] = *(const float4*)&b1[col];
        return;
    }
    if (blk >= 4232) {                      // E = b2 broadcast
        const int j = ((blk - 4232) * 256 + tid) * 4;   // j%4==0, 300%4==0
        if (j < B_SZ * EMBD) {
            const int n = j % EMBD;
            *(float4*)&E[j] = *(const float4*)&b2[n];
        }
        return;
    }
    if (blk >= 3232) {                      // scores = 0
        const int i = ((blk - 3232) * 256 + tid) * 4;
        if (i < B_SZ * NLAB) {
            float4 z = {0.f, 0.f, 0.f, 0.f};
            *(float4*)&scores[i] = z;
        }
        return;
    }

    const float* in; unsigned short* out; int N, ldK, bx, by;
    if (blk < 3072) {                       // W1: K=4096, N=2048, tiles (32,64)
        const int b = blk - 1024;
        in = W1; out = W1T; N = HIDD; ldK = VFD; bx = b & 31; by = b >> 5;
    } else {                                // W2: K=2048, N=300->320, tiles (5,32)
        const int b = blk - 3072;
        in = W2; out = W2T; N = EMBD; ldK = HIDD; bx = b % 5; by = b / 5;
    }
    const int n0 = bx * 64, k0 = by * 64;

    #pragma unroll
    for (int i = 0; i < 2; ++i) {
        const int s = tid + 256 * i;
        const int kp = s >> 4, nq = s & 15;
        const int n = n0 + nq * 4;
        float4 v0 = {0.f,0.f,0.f,0.f}, v1 = {0.f,0.f,0.f,0.f};
        if (n < N) {
            v0 = *(const float4*)&in[(size_t)(k0 + 2 * kp)     * N + n];
            v1 = *(const float4*)&in[(size_t)(k0 + 2 * kp + 1) * N + n];
        }
        Lds[nq*4+0][kp] = (unsigned)f2bf(v0.x) | ((unsigned)f2bf(v1.x) << 16);
        Lds[nq*4+1][kp] = (unsigned)f2bf(v0.y) | ((unsigned)f2bf(v1.y) << 16);
        Lds[nq*4+2][kp] = (unsigned)f2bf(v0.z) | ((unsigned)f2bf(v1.z) << 16);
        Lds[nq*4+3][kp] = (unsigned)f2bf(v0.w) | ((unsigned)f2bf(v1.w) << 16);
    }
    __syncthreads();

    #pragma unroll
    for (int i = 0; i < 2; ++i) {
        const int c = tid + 256 * i;
        const int n = c >> 3, oct = c & 7;
        uint2 lo = *(uint2*)&Lds[n][oct * 4];
        uint2 hi = *(uint2*)&Lds[n][oct * 4 + 2];
        uint4 v = make_uint4(lo.x, lo.y, hi.x, hi.y);
        *(uint4*)&out[(size_t)(n0 + n) * ldK + k0 + oct * 8] = v;
    }
}

// ---------------------------------------------------------------------------
// GEMM1 (r8-proven shape, atomic epilogue): H += Xb @ W1T^T chunk z.
// Block 64m x 128n, BK=64, split-K 4 -> grid (16,8,4) = 512 blocks = 2/CU.
// H pre-init = b1, fp32 atomicAdd (4.2M atomics total).
// ---------------------------------------------------------------------------
__global__ __launch_bounds__(256) void gemm1_kernel(
    const unsigned short* __restrict__ A,
    const unsigned short* __restrict__ Bt,
    float* __restrict__ H)
{
    __shared__ unsigned short As[2][4096];   // 8 oct x 64 rows
    __shared__ unsigned short Bs[2][8192];   // 8 oct x 128 rows

    const int tid = threadIdx.x;
    const int m0 = blockIdx.y * 64, n0 = blockIdx.x * 128;
    const int kbase = blockIdx.z * (VFD / G1_SPLIT);     // 1024

    const unsigned short* ga = A + (size_t)(m0 + (tid & 63)) * VFD + kbase + (tid >> 6) * 8;
    const unsigned short* gb = Bt + (size_t)(n0 + (tid & 127)) * VFD + kbase + (tid >> 7) * 8;

    const int lane = tid & 63;
    const int wave = tid >> 6;
    const int wm = (wave & 1) * 32;
    const int wn = (wave >> 1) * 64;
    const int q = lane >> 4, l15 = lane & 15;

    f32x4 acc[2][4];
    #pragma unroll
    for (int r = 0; r < 2; ++r)
        #pragma unroll
        for (int c = 0; c < 4; ++c) acc[r][c] = (f32x4){0.f,0.f,0.f,0.f};

    #pragma unroll
    for (int i = 0; i < 2; ++i)
        __builtin_amdgcn_global_load_lds((gas_t)(const void*)(ga + i * 32),
                                         (las_t)(void*)&As[0][(tid + 256 * i) * 8], 16, 0, 0);
    #pragma unroll
    for (int i = 0; i < 4; ++i)
        __builtin_amdgcn_global_load_lds((gas_t)(const void*)(gb + i * 16),
                                         (las_t)(void*)&Bs[0][(tid + 256 * i) * 8], 16, 0, 0);

    const int iters = (VFD / G1_SPLIT) / 64;             // 16
    for (int t = 0; t < iters; ++t) {
        const int cur = t & 1, nxt = cur ^ 1;
        __syncthreads();            // vmcnt drain: tile t present; buf[nxt] free

        if (t + 1 < iters) {
            const int ko = (t + 1) * 64;
            #pragma unroll
            for (int i = 0; i < 2; ++i)
                __builtin_amdgcn_global_load_lds((gas_t)(const void*)(ga + ko + i * 32),
                                                 (las_t)(void*)&As[nxt][(tid + 256 * i) * 8], 16, 0, 0);
            #pragma unroll
            for (int i = 0; i < 4; ++i)
                __builtin_amdgcn_global_load_lds((gas_t)(const void*)(gb + ko + i * 16),
                                                 (las_t)(void*)&Bs[nxt][(tid + 256 * i) * 8], 16, 0, 0);
        }

        #pragma unroll
        for (int kk = 0; kk < 2; ++kk) {
            const int oct = kk * 4 + q;
            short8x a0 = *(short8x*)&As[cur][(oct * 64 + wm +      l15) * 8];
            short8x a1 = *(short8x*)&As[cur][(oct * 64 + wm + 16 + l15) * 8];
            #pragma unroll
            for (int c = 0; c < 4; ++c) {
                short8x b = *(short8x*)&Bs[cur][(oct * 128 + wn + c * 16 + l15) * 8];
                acc[0][c] = __builtin_amdgcn_mfma_f32_16x16x32_bf16(a0, b, acc[0][c], 0, 0, 0);
                acc[1][c] = __builtin_amdgcn_mfma_f32_16x16x32_bf16(a1, b, acc[1][c], 0, 0, 0);
            }
        }
    }

    #pragma unroll
    for (int r = 0; r < 2; ++r)
        #pragma unroll
        for (int g = 0; g < 4; ++g) {
            const int rr = m0 + wm + r * 16 + q * 4 + g;
            #pragma unroll
            for (int c = 0; c < 4; ++c)
                atomicAdd(&H[(size_t)rr * HIDD + n0 + wn + c * 16 + l15], acc[r][c][g]);
        }
}

// ---------------------------------------------------------------------------
// GEMM2: E += (bf16(relu(H)) @ W2T^T chunk z); E pre-init = b2.
// A-operand staged MANUALLY from fp32 H (relu+cvt in regs, 2 barriers/iter);
// B via DMA (double-buffered). Tile 64m x 64n, BK=64 (4 iters), grid (5,8,8).
// ---------------------------------------------------------------------------
__global__ __launch_bounds__(256) void gemm2_kernel(
    const float* __restrict__ H,
    const unsigned short* __restrict__ Bt,
    float* __restrict__ E)
{
    __shared__ unsigned short As[4096];      // single buffer: 8 oct x 64 rows
    __shared__ unsigned short Bs[2][4096];

    const int tid = threadIdx.x;
    const int m0 = blockIdx.y * 64, n0 = blockIdx.x * 64;
    const int kbase = blockIdx.z * (HIDD / G2_SPLIT);

    // A staging: slots tid (oct 0..3) and tid+256 (oct 4..7), row = tid&63
    const float* gha = H + (size_t)(m0 + (tid & 63)) * HIDD + kbase + (tid >> 6) * 8;
    const unsigned short* gb = Bt + (size_t)(n0 + (tid & 63)) * HIDD + kbase + (tid >> 6) * 8;

    const int lane = tid & 63;
    const int wave = tid >> 6;
    const int wm = (wave & 1) * 32;
    const int wn = (wave >> 1) * 32;
    const int q = lane >> 4, l15 = lane & 15;

    f32x4 acc00 = {0.f,0.f,0.f,0.f}, acc01 = {0.f,0.f,0.f,0.f};
    f32x4 acc10 = {0.f,0.f,0.f,0.f}, acc11 = {0.f,0.f,0.f,0.f};

    // prefetch A regs (tile 0): slot0 = oct tid>>6, slot1 = oct+4 (= +32 k)
    float4 p00 = *(const float4*)(gha);
    float4 p01 = *(const float4*)(gha + 4);
    float4 p10 = *(const float4*)(gha + 32);
    float4 p11 = *(const float4*)(gha + 36);
    // DMA B tile 0
    #pragma unroll
    for (int i = 0; i < 2; ++i)
        __builtin_amdgcn_global_load_lds((gas_t)(const void*)(gb + i * 32),
                                         (las_t)(void*)&Bs[0][(tid + 256 * i) * 8], 16, 0, 0);

    const int iters = (HIDD / G2_SPLIT) / 64;            // 4
    for (int t = 0; t < iters; ++t) {
        const int cur = t & 1, nxt = cur ^ 1;

        // write A(t) regs -> As (relu + bf16 pack); prev readers done (barrier2)
        {
            uint4 u0, u1;
            u0.x = pack2relu(p00.x, p00.y); u0.y = pack2relu(p00.z, p00.w);
            u0.z = pack2relu(p01.x, p01.y); u0.w = pack2relu(p01.z, p01.w);
            u1.x = pack2relu(p10.x, p10.y); u1.y = pack2relu(p10.z, p10.w);
            u1.z = pack2relu(p11.x, p11.y); u1.w = pack2relu(p11.z, p11.w);
            *(uint4*)&As[tid * 8]         = u0;
            *(uint4*)&As[(tid + 256) * 8] = u1;
        }
        __syncthreads();   // barrier1: A written, B(t) DMA drained (vmcnt)

        if (t + 1 < iters) {
            const int ko = (t + 1) * 64;
            #pragma unroll
            for (int i = 0; i < 2; ++i)
                __builtin_amdgcn_global_load_lds((gas_t)(const void*)(gb + ko + i * 32),
                                                 (las_t)(void*)&Bs[nxt][(tid + 256 * i) * 8], 16, 0, 0);
            p00 = *(const float4*)(gha + ko);
            p01 = *(const float4*)(gha + ko + 4);
            p10 = *(const float4*)(gha + ko + 32);
            p11 = *(const float4*)(gha + ko + 36);
        }

        #pragma unroll
        for (int kk = 0; kk < 2; ++kk) {
            const int oct = kk * 4 + q;
            short8x a0 = *(short8x*)&As[(oct * 64 + wm +      l15) * 8];
            short8x a1 = *(short8x*)&As[(oct * 64 + wm + 16 + l15) * 8];
            short8x b0 = *(short8x*)&Bs[cur][(oct * 64 + wn +      l15) * 8];
            short8x b1 = *(short8x*)&Bs[cur][(oct * 64 + wn + 16 + l15) * 8];
            acc00 = __builtin_amdgcn_mfma_f32_16x16x32_bf16(a0, b0, acc00, 0, 0, 0);
            acc01 = __builtin_amdgcn_mfma_f32_16x16x32_bf16(a0, b1, acc01, 0, 0, 0);
            acc10 = __builtin_amdgcn_mfma_f32_16x16x32_bf16(a1, b0, acc10, 0, 0, 0);
            acc11 = __builtin_amdgcn_mfma_f32_16x16x32_bf16(a1, b1, acc11, 0, 0, 0);
        }
        __syncthreads();   // barrier2: reads done before next A write
    }

    const int cc = n0 + wn + l15;
    #pragma unroll
    for (int r = 0; r < 4; ++r) {
        const int rr = m0 + wm + q * 4 + r;
        if (cc < EMBD)      atomicAdd(&E[(size_t)rr * EMBD + cc],        acc00[r]);
        if (cc + 16 < EMBD) atomicAdd(&E[(size_t)rr * EMBD + cc + 16],   acc01[r]);
        if (cc < EMBD)      atomicAdd(&E[(size_t)(rr + 16) * EMBD + cc], acc10[r]);
        if (cc + 16 < EMBD) atomicAdd(&E[(size_t)(rr + 16) * EMBD + cc + 16], acc11[r]);
    }
}

// ---------------------------------------------------------------------------
// Scores v3: atomicAdd(scores[b][n], -sum_{d in quarter} relu(E-G)^2).
// Tile 64 b x 64 n, 128 threads, thread = 8 rows x 4 labels (G-reuse 8).
// Grid (32, 8, SD_SPLIT) = 1024 blocks = 4/CU.
// ---------------------------------------------------------------------------
__global__ __launch_bounds__(128) void scores_part_kernel(
    const float* __restrict__ E, const float* __restrict__ G,
    float* __restrict__ scores)
{
    __shared__ float Gs[64][44];

    const int tid = threadIdx.x;
    const int tx = tid & 15, ty = tid >> 4;   // ty 0..7 -> rows ty*8..ty*8+7
    const int n0 = blockIdx.x * 64, b0 = blockIdx.y * 64;
    const int dbase = blockIdx.z * (NPAD / SD_SPLIT);

    float acc[8][4] = {};

    for (int dc = 0; dc < NPAD / SD_SPLIT; dc += 40) {
        const int d0 = dbase + dc;
        __syncthreads();
        #pragma unroll
        for (int i = 0; i < 5; ++i) {
            const int s = tid + 128 * i;
            const int row = s / 10, qd = (s - row * 10) * 4;
            const int d = d0 + qd;
            const int n = n0 + row;
            float4 v = {0.f, 0.f, 0.f, 0.f};
            if (n < NLAB && d < EMBD) v = *(const float4*)&G[(size_t)n * EMBD + d];
            *(float4*)&Gs[row][qd] = v;
        }
        __syncthreads();

        for (int d = 0; d < 40; d += 4) {
            const int dd = d0 + d;
            float4 e[8];
            if (dd < EMBD) {
                #pragma unroll
                for (int r = 0; r < 8; ++r)
                    e[r] = *(const float4*)&E[(size_t)(b0 + ty * 8 + r) * EMBD + dd];
            } else {
                #pragma unroll
                for (int r = 0; r < 8; ++r) e[r] = make_float4(0.f, 0.f, 0.f, 0.f);
            }
            #pragma unroll
            for (int c = 0; c < 4; ++c) {
                float4 g = *(float4*)&Gs[tx + 16 * c][d];
                #pragma unroll
                for (int r = 0; r < 8; ++r) {
                    float t;
                    t = fmaxf(e[r].x - g.x, 0.f); acc[r][c] += t * t;
                    t = fmaxf(e[r].y - g.y, 0.f); acc[r][c] += t * t;
                    t = fmaxf(e[r].z - g.z, 0.f); acc[r][c] += t * t;
                    t = fmaxf(e[r].w - g.w, 0.f); acc[r][c] += t * t;
                }
            }
        }
    }

    #pragma unroll
    for (int r = 0; r < 8; ++r) {
        const int b = b0 + ty * 8 + r;
        #pragma unroll
        for (int c = 0; c < 4; ++c) {
            const int n = n0 + tx + 16 * c;
            if (n < NLAB) atomicAdd(&scores[(size_t)b * NLAB + n], -acc[r][c]);
        }
    }
}

// ---------------------------------------------------------------------------
extern "C" void kernel_launch(void* const* d_in, const int* in_sizes, int n_in,
                              void* d_out, int out_size, void* d_ws, size_t ws_size,
                              hipStream_t stream)
{
    const float* vfs = (const float*)d_in[0];   // [512,4096]
    const float* W1  = (const float*)d_in[1];   // [4096,2048]
    const float* b1  = (const float*)d_in[2];   // [2048]
    const float* W2  = (const float*)d_in[3];   // [2048,300]
    const float* b2  = (const float*)d_in[4];   // [300]
    const float* G   = (const float*)d_in[5];   // [2000,300]

    float* out    = (float*)d_out;
    float* scores = out;                        // [512*2000]
    float* E      = out + (size_t)B_SZ * NLAB;  // [512*300]

    // workspace layout (bytes): ~26.5 MB used
    char* ws = (char*)d_ws;
    unsigned short* Xb  = (unsigned short*)(ws);             //  4 MB   [512][4096]
    unsigned short* W1T = (unsigned short*)(ws + 4194304);   // 16 MB   [2048][4096]
    unsigned short* W2T = (unsigned short*)(ws + 20971520);  // 1.25 MB [320][2048]
    float*          H   = (float*)(ws + 22282240);           //  4 MB   [512][2048] fp32

    // prep: Xb(1024) + W1T(2048) + W2T(160) + scores=0(1000) + E=b2(150) + H=b1(1024)
    prep_kernel<<<5406, 256, 0, stream>>>(vfs, Xb, W1, W1T, W2, W2T,
                                          scores, b2, E, b1, H);

    // GEMM1: 64x128, BK=64, split-K 4, grid (16,8,4) = 512; atomic into H.
    gemm1_kernel<<<dim3(16, 8, G1_SPLIT), 256, 0, stream>>>(Xb, W1T, H);

    // GEMM2: manual A-staging (relu+cvt from fp32 H), atomic into E. 320 blocks.
    gemm2_kernel<<<dim3(5, 8, G2_SPLIT), 256, 0, stream>>>(H, W2T, E);

    // Scores v3: 1024 blocks, 8rx4c, atomic into scores.
    scores_part_kernel<<<dim3(32, 8, SD_SPLIT), 128, 0, stream>>>(E, G, scores);
}